// Round 4
// baseline (269.775 us; speedup 1.0000x reference)
//
#include <hip/hip_runtime.h>

namespace {

constexpr int GX = 400, GY = 400;
constexpr int P = 32;
constexpr int K = 60000;
constexpr int MCAP = 128;            // per-voxel candidate capacity == P*4 ints (reuses out row)
constexpr int NB = 4;                // batch size (fixed by dataset)
constexpr int NVOX = NB * GX * GY;   // 640000; also the sentinel id
constexpr int SCAN_CHUNK = 1024;
constexpr int NBLK = (NVOX + 1 + SCAN_CHUNK - 1) / SCAN_CHUNK;  // 626
constexpr int OCC_PAD = NBLK * SCAN_CHUNK;                      // 641024

constexpr float XMINf = -20.f, YMINf = -20.f, ZMINf = -2.f;
constexpr float XMAXf =  20.f, YMAXf =  20.f, ZMAXf =  3.f;

constexpr int OUT_VOX = 0;
constexpr int OUT_CNT = K * P * 4;        // 7,680,000
constexpr int OUT_COR = OUT_CNT + K;      // 7,740,000

// Binning formula under test this round: f32 reciprocal-multiply.
// R2 (IEEE f32 divide) and R3 (f64 divide == exact real arithmetic) each
// mismatched the np reference at exactly one boundary point -> the np ref
// must use an f32 formula that is not the f32 divide: (x - XMIN) * 10.0f.
__device__ __forceinline__ int bin_of(float v) {
  return (int)((v + 20.0f) * 10.0f);
}

__device__ __forceinline__ bool point_voxel(const float* __restrict__ pt, int& flat) {
  float x = pt[1], y = pt[2], z = pt[3];
  bool m = (x >= XMINf) & (x < XMAXf) & (y >= YMINf) & (y < YMAXf)
         & (z >= ZMINf) & (z < ZMAXf);
  if (!m) return false;
  int bi = (int)pt[0];
  int xi = min(max(bin_of(x), 0), GX - 1);
  int yi = min(max(bin_of(y), 0), GY - 1);
  flat = bi * (GX * GY) + xi * GY + yi;
  return true;
}

// ---- pass 1: occupancy flags --------------------------------------------
__global__ void k_mark(const float* __restrict__ pts, int n, int* __restrict__ occ) {
  int i = blockIdx.x * blockDim.x + threadIdx.x;
  if (i >= n) return;
  int flat;
  if (point_voxel(pts + (size_t)i * 5, flat)) occ[flat] = 1;  // benign race
}

// ---- pass 2a: per-chunk sums --------------------------------------------
__global__ void k_bsum(const int* __restrict__ occ, int* __restrict__ bsum) {
  __shared__ int wsums[4];
  int t = threadIdx.x, wid = t >> 6, lane = t & 63;
  int base = blockIdx.x * SCAN_CHUNK;
  int4 v = ((const int4*)(occ + base))[t];
  int s = v.x + v.y + v.z + v.w;
  for (int o = 32; o > 0; o >>= 1) s += __shfl_xor(s, o, 64);
  if (lane == 0) wsums[wid] = s;
  __syncthreads();
  if (t == 0) bsum[blockIdx.x] = wsums[0] + wsums[1] + wsums[2] + wsums[3];
}

// ---- pass 2b: scan chunk sums (single block) ----------------------------
__global__ void k_scanb(int* __restrict__ bsum) {
  __shared__ int lds[1024];
  int t = threadIdx.x;
  int v = (t < NBLK) ? bsum[t] : 0;
  lds[t] = v;
  __syncthreads();
  for (int o = 1; o < 1024; o <<= 1) {
    int add = (t >= o) ? lds[t - o] : 0;
    __syncthreads();
    lds[t] += add;
    __syncthreads();
  }
  if (t < NBLK) bsum[t] = lds[t] - v;             // exclusive
  if (t == NBLK - 1) bsum[NBLK] = lds[t];         // total = num_unique
}

// ---- pass 2c: full exclusive scan in-place (occ -> rank), emit uniq -----
__global__ void k_rank(int* __restrict__ occ, const int* __restrict__ bsum,
                       int* __restrict__ uniq) {
  __shared__ int wsums[4];
  int t = threadIdx.x, wid = t >> 6, lane = t & 63;
  int base = blockIdx.x * SCAN_CHUNK;
  int4 v = ((const int4*)(occ + base))[t];
  int tsum = v.x + v.y + v.z + v.w;
  int sc = tsum;                                   // inclusive wave scan
  for (int o = 1; o < 64; o <<= 1) {
    int u = __shfl_up(sc, o, 64);
    if (lane >= o) sc += u;
  }
  if (lane == 63) wsums[wid] = sc;
  __syncthreads();
  int woff = 0;
  for (int w = 0; w < wid; ++w) woff += wsums[w];
  int p = bsum[blockIdx.x] + woff + (sc - tsum);   // exclusive prefix of elem 0
  int e0 = base + t * 4;
  int4 r;
  r.x = p; if (v.x) { if (p < K) uniq[p] = e0 + 0; ++p; }
  r.y = p; if (v.y) { if (p < K) uniq[p] = e0 + 1; ++p; }
  r.z = p; if (v.z) { if (p < K) uniq[p] = e0 + 2; ++p; }
  r.w = p; if (v.w) { if (p < K) uniq[p] = e0 + 3; ++p; }
  ((int4*)(occ + base))[t] = r;
}

// ---- pass 3: append point indices into d_out voxel rows (as uint) -------
__global__ void k_append(const float* __restrict__ pts, int n,
                         const int* __restrict__ rank, int* __restrict__ cnt,
                         unsigned* __restrict__ vox) {
  int i = blockIdx.x * blockDim.x + threadIdx.x;
  if (i >= n) return;
  int flat;
  if (!point_voxel(pts + (size_t)i * 5, flat)) return;
  int v = rank[flat];
  if (v >= K) return;
  int pos = atomicAdd(&cnt[v], 1);
  if (pos < MCAP) vox[(size_t)v * MCAP + pos] = (unsigned)i;
}

// ---- pass 4: per-voxel ordered selection + output (in-place) ------------
__global__ void __launch_bounds__(256) k_final(
    const float* __restrict__ pts, const int* __restrict__ uniq,
    const int* __restrict__ cnt, const int* __restrict__ nuq_p,
    float* __restrict__ out) {
  int wid = threadIdx.x >> 6, lane = threadIdx.x & 63;
  int k = blockIdx.x * 4 + wid;
  if (k >= K) return;
  int nuq = min(nuq_p[0], K);
  int c_tot = 0, c_out = 0;
  if (k < nuq) {
    int c = cnt[k];
    c_tot = min(c, MCAP);
    c_out = min(c, P);
  }
  const unsigned UMAX = 0xffffffffu;
  const unsigned* row = (const unsigned*)out + (size_t)k * MCAP;
  unsigned v0 = (lane < c_tot) ? row[lane] : UMAX;
  unsigned v1 = (lane + 64 < c_tot) ? row[lane + 64] : UMAX;

  int mys = lane >> 1, h = lane & 1;
  unsigned myidx = 0;
  for (int s = 0; s < c_out; ++s) {              // extract s-th smallest point index
    unsigned m = min(v0, v1);
    for (int o = 1; o < 64; o <<= 1) m = min(m, __shfl_xor(m, o, 64));
    if (s == mys) myidx = m;
    if (v0 == m) v0 = UMAX; else if (v1 == m) v1 = UMAX;
  }

  float a = 0.f, b = 0.f;
  if (mys < c_out) {
    const float* pp = pts + (size_t)myidx * 5;
    a = pp[1 + 2 * h];
    b = pp[2 + 2 * h];
  }
  // candidates were consumed into registers above; overwrite row in place.
  // lane writes floats [2*lane, 2*lane+1] of this voxel's 128-float row
  float2* vout = (float2*)(out + OUT_VOX + (size_t)k * (P * 4));
  vout[lane] = make_float2(a, b);

  if (lane == 0) {
    out[OUT_CNT + k] = (float)c_out;
    int f = (k < nuq) ? uniq[k] : NVOX;
    int cb = f / (GX * GY), rem = f % (GX * GY);
    out[OUT_COR + (size_t)k * 3 + 0] = (float)cb;
    out[OUT_COR + (size_t)k * 3 + 1] = (float)(rem / GY);
    out[OUT_COR + (size_t)k * 3 + 2] = (float)(rem % GY);
  }
}

}  // namespace

extern "C" void kernel_launch(void* const* d_in, const int* in_sizes, int n_in,
                              void* d_out, int out_size, void* d_ws, size_t ws_size,
                              hipStream_t stream) {
  const float* pts = (const float*)d_in[0];
  int n = in_sizes[0] / 5;

  int* occ  = (int*)d_ws;                  // OCC_PAD ints (becomes rank)
  int* bsum = occ + OCC_PAD;               // NBLK+1 ints
  int* uniq = bsum + (NBLK + 1);           // K ints
  int* cnt  = uniq + K;                    // K ints
  float* out = (float*)d_out;              // voxel rows double as candidate lists

  hipMemsetAsync(occ, 0, (size_t)OCC_PAD * sizeof(int), stream);
  hipMemsetAsync(cnt, 0, (size_t)K * sizeof(int), stream);
  hipMemsetAsync(out, 0xFF, (size_t)K * MCAP * sizeof(int), stream);  // UINT_MAX sentinels

  int nb_pts = (n + 255) / 256;
  k_mark  <<<nb_pts, 256, 0, stream>>>(pts, n, occ);
  k_bsum  <<<NBLK, 256, 0, stream>>>(occ, bsum);
  k_scanb <<<1, 1024, 0, stream>>>(bsum);
  k_rank  <<<NBLK, 256, 0, stream>>>(occ, bsum, uniq);
  k_append<<<nb_pts, 256, 0, stream>>>(pts, n, occ, cnt, (unsigned*)out);
  k_final <<<(K + 3) / 4, 256, 0, stream>>>(pts, uniq, cnt, bsum + NBLK, out);
}

// Round 5
// 246.726 us; speedup vs baseline: 1.0934x; 1.0934x over previous
//
#include <hip/hip_runtime.h>

namespace {

constexpr int GX = 400, GY = 400;
constexpr int P = 32;
constexpr int K = 60000;
constexpr int MCAP = 128;            // per-voxel candidate capacity == P*4 ints (reuses out row)
constexpr int NB = 4;                // batch size (fixed by dataset)
constexpr int NVOX = NB * GX * GY;   // 640000
constexpr int SCAN_CHUNK = 1024;
constexpr int NBLK = (NVOX + 1 + SCAN_CHUNK - 1) / SCAN_CHUNK;  // 626
constexpr int OCC_PAD = NBLK * SCAN_CHUNK;                      // 641024

constexpr float XMINf = -20.f, YMINf = -20.f, ZMINf = -2.f;
constexpr float XMAXf =  20.f, YMAXf =  20.f, ZMAXf =  3.f;

constexpr int OUT_CNT = K * P * 4;        // 7,680,000
constexpr int OUT_COR = OUT_CNT + K;      // 7,740,000

// DO NOT TOUCH: this exact f32 expression matches the np reference's binning
// (R2 f32-divide and R3 f64-divide each flipped one boundary point; R4 passed).
__device__ __forceinline__ int bin_of(float v) {
  return (int)((v + 20.0f) * 10.0f);
}

__device__ __forceinline__ bool point_voxel(const float* __restrict__ pt, int& flat) {
  float x = pt[1], y = pt[2], z = pt[3];
  bool m = (x >= XMINf) & (x < XMAXf) & (y >= YMINf) & (y < YMAXf)
         & (z >= ZMINf) & (z < ZMAXf);
  if (!m) return false;
  int bi = (int)pt[0];
  int xi = min(max(bin_of(x), 0), GX - 1);
  int yi = min(max(bin_of(y), 0), GY - 1);
  flat = bi * (GX * GY) + xi * GY + yi;
  return true;
}

// ---- pass 1: bin points -> occupancy flags (+ cached flat ids) ----------
__global__ void k_mark(const float* __restrict__ pts, int n,
                       int* __restrict__ occ, int* __restrict__ pflat) {
  int i = blockIdx.x * blockDim.x + threadIdx.x;
  if (i >= n) return;
  int flat = -1;
  if (point_voxel(pts + (size_t)i * 5, flat)) occ[flat] = 1;  // benign race
  if (pflat) pflat[i] = flat;
}

// ---- pass 2a: per-chunk sums --------------------------------------------
__global__ void k_bsum(const int* __restrict__ occ, int* __restrict__ bsum) {
  __shared__ int wsums[4];
  int t = threadIdx.x, wid = t >> 6, lane = t & 63;
  int base = blockIdx.x * SCAN_CHUNK;
  int4 v = ((const int4*)(occ + base))[t];
  int s = v.x + v.y + v.z + v.w;
  for (int o = 32; o > 0; o >>= 1) s += __shfl_xor(s, o, 64);
  if (lane == 0) wsums[wid] = s;
  __syncthreads();
  if (t == 0) bsum[blockIdx.x] = wsums[0] + wsums[1] + wsums[2] + wsums[3];
}

// ---- pass 2b: scan chunk sums (single block) ----------------------------
__global__ void k_scanb(int* __restrict__ bsum) {
  __shared__ int lds[1024];
  int t = threadIdx.x;
  int v = (t < NBLK) ? bsum[t] : 0;
  lds[t] = v;
  __syncthreads();
  for (int o = 1; o < 1024; o <<= 1) {
    int add = (t >= o) ? lds[t - o] : 0;
    __syncthreads();
    lds[t] += add;
    __syncthreads();
  }
  if (t < NBLK) bsum[t] = lds[t] - v;             // exclusive
  if (t == NBLK - 1) bsum[NBLK] = lds[t];         // total = num_unique
}

// ---- pass 2c: full exclusive scan in-place (occ -> rank), emit uniq -----
__global__ void k_rank(int* __restrict__ occ, const int* __restrict__ bsum,
                       int* __restrict__ uniq) {
  __shared__ int wsums[4];
  int t = threadIdx.x, wid = t >> 6, lane = t & 63;
  int base = blockIdx.x * SCAN_CHUNK;
  int4 v = ((const int4*)(occ + base))[t];
  int tsum = v.x + v.y + v.z + v.w;
  int sc = tsum;                                   // inclusive wave scan
  for (int o = 1; o < 64; o <<= 1) {
    int u = __shfl_up(sc, o, 64);
    if (lane >= o) sc += u;
  }
  if (lane == 63) wsums[wid] = sc;
  __syncthreads();
  int woff = 0;
  for (int w = 0; w < wid; ++w) woff += wsums[w];
  int p = bsum[blockIdx.x] + woff + (sc - tsum);   // exclusive prefix of elem 0
  int e0 = base + t * 4;
  int4 r;
  r.x = p; if (v.x) { if (p < K) uniq[p] = e0 + 0; ++p; }
  r.y = p; if (v.y) { if (p < K) uniq[p] = e0 + 1; ++p; }
  r.z = p; if (v.z) { if (p < K) uniq[p] = e0 + 2; ++p; }
  r.w = p; if (v.w) { if (p < K) uniq[p] = e0 + 3; ++p; }
  ((int4*)(occ + base))[t] = r;
}

// ---- pass 3: append point indices into d_out voxel rows (as uint) -------
__global__ void k_append(const int* __restrict__ pflat, int n4,
                         const int* __restrict__ rank, int* __restrict__ cnt,
                         unsigned* __restrict__ vox, int n) {
  int t = blockIdx.x * blockDim.x + threadIdx.x;
  if (t >= n4) return;
  int4 f4 = ((const int4*)pflat)[t];
  int base = t * 4;
  #pragma unroll
  for (int j = 0; j < 4; ++j) {
    int i = base + j;
    int f = (j == 0) ? f4.x : (j == 1) ? f4.y : (j == 2) ? f4.z : f4.w;
    if (i < n && f >= 0) {
      int v = rank[f];
      if (v < K) {
        int pos = atomicAdd(&cnt[v], 1);
        if (pos < MCAP) vox[(size_t)v * MCAP + pos] = (unsigned)i;
      }
    }
  }
}

// fallback if ws too small for pflat: recompute bins from points
__global__ void k_append_fb(const float* __restrict__ pts, int n,
                            const int* __restrict__ rank, int* __restrict__ cnt,
                            unsigned* __restrict__ vox) {
  int i = blockIdx.x * blockDim.x + threadIdx.x;
  if (i >= n) return;
  int flat;
  if (!point_voxel(pts + (size_t)i * 5, flat)) return;
  int v = rank[flat];
  if (v >= K) return;
  int pos = atomicAdd(&cnt[v], 1);
  if (pos < MCAP) vox[(size_t)v * MCAP + pos] = (unsigned)i;
}

// ---- pass 4: per-voxel bitonic sort-128 + gather + output (in-place) ----
__global__ void __launch_bounds__(256) k_final(
    const float* __restrict__ pts, const int* __restrict__ uniq,
    const int* __restrict__ cnt, const int* __restrict__ nuq_p,
    float* __restrict__ out) {
  int wid = threadIdx.x >> 6, lane = threadIdx.x & 63;
  int k = blockIdx.x * 4 + wid;
  if (k >= K) return;
  int nuq = min(nuq_p[0], K);
  int c_tot = 0, c_out = 0;
  if (k < nuq) {
    int c = cnt[k];
    c_tot = min(c, MCAP);
    c_out = min(c, P);
  }
  const unsigned UMAX = 0xffffffffu;
  const unsigned* row = (const unsigned*)out + (size_t)k * MCAP;
  uint2 q = ((const uint2*)row)[lane];             // elements e = 2*lane, 2*lane+1
  unsigned v0 = (2 * lane     < c_tot) ? q.x : UMAX;
  unsigned v1 = (2 * lane + 1 < c_tot) ? q.y : UMAX;

  // bitonic sort of 128 keys; element e = 2*lane + r  (r = reg index)
  #pragma unroll
  for (int ph = 1; ph <= 7; ++ph) {
    int kk = 1 << ph;
    bool up = ((lane & (kk >> 1)) == 0);           // (e & kk)==0
    #pragma unroll
    for (int d = kk >> 1; d >= 2; d >>= 1) {       // cross-lane stages
      int dl = d >> 1;
      unsigned p0 = __shfl_xor(v0, dl, 64);
      unsigned p1 = __shfl_xor(v1, dl, 64);
      bool low = ((lane & dl) == 0);
      if (low == up) { v0 = min(v0, p0); v1 = min(v1, p1); }
      else           { v0 = max(v0, p0); v1 = max(v1, p1); }
    }
    unsigned lo = min(v0, v1), hi = max(v0, v1);   // d = 1, in-register
    v0 = up ? lo : hi;
    v1 = up ? hi : lo;
  }
  // sorted: element e holds e-th smallest; e = 2*lane + r

  int mys = lane >> 1, h = lane & 1;               // output slot / half
  unsigned a0 = __shfl(v0, mys >> 1, 64);
  unsigned a1 = __shfl(v1, mys >> 1, 64);
  unsigned myidx = (mys & 1) ? a1 : a0;

  float a = 0.f, b = 0.f;
  if (mys < c_out) {
    const float* pp = pts + (size_t)myidx * 5;
    a = pp[1 + 2 * h];
    b = pp[2 + 2 * h];
  }
  // row fully consumed into regs above; overwrite in place
  float2* vout = (float2*)(out + (size_t)k * (P * 4));
  vout[lane] = make_float2(a, b);

  if (lane == 0) {
    out[OUT_CNT + k] = (float)c_out;
    int f = (k < nuq) ? uniq[k] : NVOX;
    int cb = f / (GX * GY), rem = f % (GX * GY);
    out[OUT_COR + (size_t)k * 3 + 0] = (float)cb;
    out[OUT_COR + (size_t)k * 3 + 1] = (float)(rem / GY);
    out[OUT_COR + (size_t)k * 3 + 2] = (float)(rem % GY);
  }
}

}  // namespace

extern "C" void kernel_launch(void* const* d_in, const int* in_sizes, int n_in,
                              void* d_out, int out_size, void* d_ws, size_t ws_size,
                              hipStream_t stream) {
  const float* pts = (const float*)d_in[0];
  int n = in_sizes[0] / 5;
  int n4 = (n + 3) / 4;

  int* occ  = (int*)d_ws;                  // OCC_PAD ints (becomes rank)
  int* bsum = occ + OCC_PAD;               // NBLK+1 ints
  int* uniq = bsum + (NBLK + 1);           // K ints
  int* cnt  = uniq + K;                    // K ints
  size_t base_ints = (size_t)OCC_PAD + (NBLK + 1) + K + K;
  base_ints = (base_ints + 3) & ~(size_t)3;          // 16B-align pflat for int4
  int* pflat = (int*)d_ws + base_ints;               // n4*4 ints (optional)
  bool use_pflat = ws_size >= (base_ints + (size_t)n4 * 4) * sizeof(int);
  float* out = (float*)d_out;              // voxel rows double as candidate lists

  hipMemsetAsync(occ, 0, (size_t)OCC_PAD * sizeof(int), stream);
  hipMemsetAsync(cnt, 0, (size_t)K * sizeof(int), stream);

  int nb_pts = (n + 255) / 256;
  k_mark  <<<nb_pts, 256, 0, stream>>>(pts, n, occ, use_pflat ? pflat : nullptr);
  k_bsum  <<<NBLK, 256, 0, stream>>>(occ, bsum);
  k_scanb <<<1, 1024, 0, stream>>>(bsum);
  k_rank  <<<NBLK, 256, 0, stream>>>(occ, bsum, uniq);
  if (use_pflat)
    k_append<<<(n4 + 255) / 256, 256, 0, stream>>>(pflat, n4, occ, cnt, (unsigned*)out, n);
  else
    k_append_fb<<<nb_pts, 256, 0, stream>>>(pts, n, occ, cnt, (unsigned*)out);
  k_final <<<(K + 3) / 4, 256, 0, stream>>>(pts, uniq, cnt, bsum + NBLK, out);
}

// Round 6
// 239.997 us; speedup vs baseline: 1.1241x; 1.0280x over previous
//
#include <hip/hip_runtime.h>

namespace {

constexpr int GX = 400, GY = 400;
constexpr int P = 32;
constexpr int K = 60000;
constexpr int MCAP = 128;            // per-voxel candidate capacity == P*4 ints (reuses out row)
constexpr int NB = 4;                // batch size (fixed by dataset)
constexpr int NVOX = NB * GX * GY;   // 640000
constexpr int SCAN_CHUNK = 1024;
constexpr int NBLK = (NVOX + 1 + SCAN_CHUNK - 1) / SCAN_CHUNK;  // 626
constexpr int OCC_PAD = NBLK * SCAN_CHUNK;                      // 641024

constexpr float XMINf = -20.f, YMINf = -20.f, ZMINf = -2.f;
constexpr float XMAXf =  20.f, YMAXf =  20.f, ZMAXf =  3.f;

constexpr int OUT_CNT = K * P * 4;        // 7,680,000
constexpr int OUT_COR = OUT_CNT + K;      // 7,740,000

// DO NOT TOUCH: this exact f32 expression matches the np reference's binning
// (R2 f32-divide and R3 f64-divide each flipped one boundary point; R4 passed).
__device__ __forceinline__ int bin_of(float v) {
  return (int)((v + 20.0f) * 10.0f);
}

__device__ __forceinline__ bool point_voxel(const float* __restrict__ pt, int& flat) {
  float x = pt[1], y = pt[2], z = pt[3];
  bool m = (x >= XMINf) & (x < XMAXf) & (y >= YMINf) & (y < YMAXf)
         & (z >= ZMINf) & (z < ZMAXf);
  if (!m) return false;
  int bi = (int)pt[0];
  int xi = min(max(bin_of(x), 0), GX - 1);
  int yi = min(max(bin_of(y), 0), GY - 1);
  flat = bi * (GX * GY) + xi * GY + yi;
  return true;
}

// ---- pass 1: bin points -> occupancy flags (+ cached flat ids) ----------
__global__ void k_mark(const float* __restrict__ pts, int n,
                       int* __restrict__ occ, int* __restrict__ pflat) {
  int i = blockIdx.x * blockDim.x + threadIdx.x;
  if (i >= n) return;
  int flat = -1;
  if (point_voxel(pts + (size_t)i * 5, flat)) occ[flat] = 1;  // benign race
  if (pflat) pflat[i] = flat;
}

// ---- pass 2a: per-chunk sums --------------------------------------------
__global__ void k_bsum(const int* __restrict__ occ, int* __restrict__ bsum) {
  __shared__ int wsums[4];
  int t = threadIdx.x, wid = t >> 6, lane = t & 63;
  int base = blockIdx.x * SCAN_CHUNK;
  int4 v = ((const int4*)(occ + base))[t];
  int s = v.x + v.y + v.z + v.w;
  for (int o = 32; o > 0; o >>= 1) s += __shfl_xor(s, o, 64);
  if (lane == 0) wsums[wid] = s;
  __syncthreads();
  if (t == 0) bsum[blockIdx.x] = wsums[0] + wsums[1] + wsums[2] + wsums[3];
}

// ---- pass 2b: scan chunk sums (single block) ----------------------------
__global__ void k_scanb(int* __restrict__ bsum) {
  __shared__ int lds[1024];
  int t = threadIdx.x;
  int v = (t < NBLK) ? bsum[t] : 0;
  lds[t] = v;
  __syncthreads();
  for (int o = 1; o < 1024; o <<= 1) {
    int add = (t >= o) ? lds[t - o] : 0;
    __syncthreads();
    lds[t] += add;
    __syncthreads();
  }
  if (t < NBLK) bsum[t] = lds[t] - v;             // exclusive
  if (t == NBLK - 1) bsum[NBLK] = lds[t];         // total = num_unique
}

// ---- pass 2c: full exclusive scan in-place (occ -> rank), emit uniq -----
__global__ void k_rank(int* __restrict__ occ, const int* __restrict__ bsum,
                       int* __restrict__ uniq) {
  __shared__ int wsums[4];
  int t = threadIdx.x, wid = t >> 6, lane = t & 63;
  int base = blockIdx.x * SCAN_CHUNK;
  int4 v = ((const int4*)(occ + base))[t];
  int tsum = v.x + v.y + v.z + v.w;
  int sc = tsum;                                   // inclusive wave scan
  for (int o = 1; o < 64; o <<= 1) {
    int u = __shfl_up(sc, o, 64);
    if (lane >= o) sc += u;
  }
  if (lane == 63) wsums[wid] = sc;
  __syncthreads();
  int woff = 0;
  for (int w = 0; w < wid; ++w) woff += wsums[w];
  int p = bsum[blockIdx.x] + woff + (sc - tsum);   // exclusive prefix of elem 0
  int e0 = base + t * 4;
  int4 r;
  r.x = p; if (v.x) { if (p < K) uniq[p] = e0 + 0; ++p; }
  r.y = p; if (v.y) { if (p < K) uniq[p] = e0 + 1; ++p; }
  r.z = p; if (v.z) { if (p < K) uniq[p] = e0 + 2; ++p; }
  r.w = p; if (v.w) { if (p < K) uniq[p] = e0 + 3; ++p; }
  ((int4*)(occ + base))[t] = r;
}

// ---- pass 3: append point indices into d_out voxel rows (as uint) -------
// 1 point/thread: maximize independent atomic->store chains in flight
// (R5's 4 pts/thread halved perf by serializing dependent chains).
__global__ void k_append(const int* __restrict__ pflat, int n,
                         const int* __restrict__ rank, int* __restrict__ cnt,
                         unsigned* __restrict__ vox) {
  int i = blockIdx.x * blockDim.x + threadIdx.x;
  if (i >= n) return;
  int f = pflat[i];
  if (f < 0) return;
  int v = rank[f];
  if (v >= K) return;
  int pos = atomicAdd(&cnt[v], 1);
  if (pos < MCAP) vox[(size_t)v * MCAP + pos] = (unsigned)i;
}

// fallback if ws too small for pflat: recompute bins from points
__global__ void k_append_fb(const float* __restrict__ pts, int n,
                            const int* __restrict__ rank, int* __restrict__ cnt,
                            unsigned* __restrict__ vox) {
  int i = blockIdx.x * blockDim.x + threadIdx.x;
  if (i >= n) return;
  int flat;
  if (!point_voxel(pts + (size_t)i * 5, flat)) return;
  int v = rank[flat];
  if (v >= K) return;
  int pos = atomicAdd(&cnt[v], 1);
  if (pos < MCAP) vox[(size_t)v * MCAP + pos] = (unsigned)i;
}

// ---- pass 4: per-voxel bitonic sort-128 + gather + output (in-place) ----
__global__ void __launch_bounds__(256) k_final(
    const float* __restrict__ pts, const int* __restrict__ uniq,
    const int* __restrict__ cnt, const int* __restrict__ nuq_p,
    float* __restrict__ out) {
  int wid = threadIdx.x >> 6, lane = threadIdx.x & 63;
  int k = blockIdx.x * 4 + wid;
  if (k >= K) return;
  int nuq = min(nuq_p[0], K);
  int c_tot = 0, c_out = 0;
  if (k < nuq) {
    int c = cnt[k];
    c_tot = min(c, MCAP);
    c_out = min(c, P);
  }
  const unsigned UMAX = 0xffffffffu;
  const unsigned* row = (const unsigned*)out + (size_t)k * MCAP;
  uint2 q = ((const uint2*)row)[lane];             // elements e = 2*lane, 2*lane+1
  unsigned v0 = (2 * lane     < c_tot) ? q.x : UMAX;
  unsigned v1 = (2 * lane + 1 < c_tot) ? q.y : UMAX;

  // bitonic sort of 128 keys; element e = 2*lane + r  (r = reg index)
  #pragma unroll
  for (int ph = 1; ph <= 7; ++ph) {
    int kk = 1 << ph;
    bool up = ((lane & (kk >> 1)) == 0);           // (e & kk)==0
    #pragma unroll
    for (int d = kk >> 1; d >= 2; d >>= 1) {       // cross-lane stages
      int dl = d >> 1;
      unsigned p0 = __shfl_xor(v0, dl, 64);
      unsigned p1 = __shfl_xor(v1, dl, 64);
      bool low = ((lane & dl) == 0);
      if (low == up) { v0 = min(v0, p0); v1 = min(v1, p1); }
      else           { v0 = max(v0, p0); v1 = max(v1, p1); }
    }
    unsigned lo = min(v0, v1), hi = max(v0, v1);   // d = 1, in-register
    v0 = up ? lo : hi;
    v1 = up ? hi : lo;
  }
  // sorted: element e holds e-th smallest; e = 2*lane + r

  int mys = lane >> 1, h = lane & 1;               // output slot / half
  unsigned a0 = __shfl(v0, mys >> 1, 64);
  unsigned a1 = __shfl(v1, mys >> 1, 64);
  unsigned myidx = (mys & 1) ? a1 : a0;

  float a = 0.f, b = 0.f;
  if (mys < c_out) {
    const float* pp = pts + (size_t)myidx * 5;
    a = pp[1 + 2 * h];
    b = pp[2 + 2 * h];
  }
  // row fully consumed into regs above; overwrite in place
  float2* vout = (float2*)(out + (size_t)k * (P * 4));
  vout[lane] = make_float2(a, b);

  if (lane == 0) {
    out[OUT_CNT + k] = (float)c_out;
    int f = (k < nuq) ? uniq[k] : NVOX;
    int cb = f / (GX * GY), rem = f % (GX * GY);
    out[OUT_COR + (size_t)k * 3 + 0] = (float)cb;
    out[OUT_COR + (size_t)k * 3 + 1] = (float)(rem / GY);
    out[OUT_COR + (size_t)k * 3 + 2] = (float)(rem % GY);
  }
}

}  // namespace

extern "C" void kernel_launch(void* const* d_in, const int* in_sizes, int n_in,
                              void* d_out, int out_size, void* d_ws, size_t ws_size,
                              hipStream_t stream) {
  const float* pts = (const float*)d_in[0];
  int n = in_sizes[0] / 5;

  int* occ  = (int*)d_ws;                  // OCC_PAD ints (becomes rank)
  int* bsum = occ + OCC_PAD;               // NBLK+1 ints
  int* uniq = bsum + (NBLK + 1);           // K ints
  int* cnt  = uniq + K;                    // K ints
  size_t base_ints = (size_t)OCC_PAD + (NBLK + 1) + K + K;
  base_ints = (base_ints + 3) & ~(size_t)3;          // 16B-align pflat
  int* pflat = (int*)d_ws + base_ints;               // n ints (optional)
  bool use_pflat = ws_size >= (base_ints + (size_t)n) * sizeof(int);
  float* out = (float*)d_out;              // voxel rows double as candidate lists

  hipMemsetAsync(occ, 0, (size_t)OCC_PAD * sizeof(int), stream);
  hipMemsetAsync(cnt, 0, (size_t)K * sizeof(int), stream);

  int nb_pts = (n + 255) / 256;
  k_mark  <<<nb_pts, 256, 0, stream>>>(pts, n, occ, use_pflat ? pflat : nullptr);
  k_bsum  <<<NBLK, 256, 0, stream>>>(occ, bsum);
  k_scanb <<<1, 1024, 0, stream>>>(bsum);
  k_rank  <<<NBLK, 256, 0, stream>>>(occ, bsum, uniq);
  if (use_pflat)
    k_append<<<nb_pts, 256, 0, stream>>>(pflat, n, occ, cnt, (unsigned*)out);
  else
    k_append_fb<<<nb_pts, 256, 0, stream>>>(pts, n, occ, cnt, (unsigned*)out);
  k_final <<<(K + 3) / 4, 256, 0, stream>>>(pts, uniq, cnt, bsum + NBLK, out);
}

// Round 7
// 214.613 us; speedup vs baseline: 1.2570x; 1.1183x over previous
//
#include <hip/hip_runtime.h>

namespace {

constexpr int GX = 400, GY = 400;
constexpr int P = 32;
constexpr int K = 60000;
constexpr int MCAP = 128;            // per-voxel candidate capacity
constexpr int NB = 4;                // batch size (fixed by dataset)
constexpr int NVOX = NB * GX * GY;   // 640000
constexpr int SCAN_CHUNK = 1024;
constexpr int NBLK = (NVOX + 1 + SCAN_CHUNK - 1) / SCAN_CHUNK;  // 626
constexpr int OCC_PAD = NBLK * SCAN_CHUNK;                      // 641024
constexpr int NPART = 8;             // XCD count; voxel-rank partitions
constexpr int PARTW = K / NPART;     // 7500

constexpr float XMINf = -20.f, YMINf = -20.f, ZMINf = -2.f;
constexpr float XMAXf =  20.f, YMAXf =  20.f, ZMAXf =  3.f;

constexpr int OUT_CNT = K * P * 4;        // 7,680,000
constexpr int OUT_COR = OUT_CNT + K;      // 7,740,000

// DO NOT TOUCH: this exact f32 expression matches the np reference's binning
// (R2 f32-divide and R3 f64-divide each flipped one boundary point; R4+ passed).
__device__ __forceinline__ int bin_of(float v) {
  return (int)((v + 20.0f) * 10.0f);
}

__device__ __forceinline__ bool point_voxel(const float* __restrict__ pt, int& flat) {
  float x = pt[1], y = pt[2], z = pt[3];
  bool m = (x >= XMINf) & (x < XMAXf) & (y >= YMINf) & (y < YMAXf)
         & (z >= ZMINf) & (z < ZMAXf);
  if (!m) return false;
  int bi = (int)pt[0];
  int xi = min(max(bin_of(x), 0), GX - 1);
  int yi = min(max(bin_of(y), 0), GY - 1);
  flat = bi * (GX * GY) + xi * GY + yi;
  return true;
}

// ---- pass 1: bin points -> occupancy flags (+ cached flat ids) ----------
__global__ void k_mark(const float* __restrict__ pts, int n,
                       int* __restrict__ occ, int* __restrict__ pflat) {
  int i = blockIdx.x * blockDim.x + threadIdx.x;
  if (i >= n) return;
  int flat = -1;
  if (point_voxel(pts + (size_t)i * 5, flat)) occ[flat] = 1;  // benign race
  if (pflat) pflat[i] = flat;
}

// ---- pass 2a: per-chunk sums --------------------------------------------
__global__ void k_bsum(const int* __restrict__ occ, int* __restrict__ bsum) {
  __shared__ int wsums[4];
  int t = threadIdx.x, wid = t >> 6, lane = t & 63;
  int base = blockIdx.x * SCAN_CHUNK;
  int4 v = ((const int4*)(occ + base))[t];
  int s = v.x + v.y + v.z + v.w;
  for (int o = 32; o > 0; o >>= 1) s += __shfl_xor(s, o, 64);
  if (lane == 0) wsums[wid] = s;
  __syncthreads();
  if (t == 0) bsum[blockIdx.x] = wsums[0] + wsums[1] + wsums[2] + wsums[3];
}

// ---- pass 2b: scan chunk sums (single block) ----------------------------
__global__ void k_scanb(int* __restrict__ bsum) {
  __shared__ int lds[1024];
  int t = threadIdx.x;
  int v = (t < NBLK) ? bsum[t] : 0;
  lds[t] = v;
  __syncthreads();
  for (int o = 1; o < 1024; o <<= 1) {
    int add = (t >= o) ? lds[t - o] : 0;
    __syncthreads();
    lds[t] += add;
    __syncthreads();
  }
  if (t < NBLK) bsum[t] = lds[t] - v;             // exclusive
  if (t == NBLK - 1) bsum[NBLK] = lds[t];         // total = num_unique
}

// ---- pass 2c: full exclusive scan in-place (occ -> rank), emit uniq -----
__global__ void k_rank(int* __restrict__ occ, const int* __restrict__ bsum,
                       int* __restrict__ uniq) {
  __shared__ int wsums[4];
  int t = threadIdx.x, wid = t >> 6, lane = t & 63;
  int base = blockIdx.x * SCAN_CHUNK;
  int4 v = ((const int4*)(occ + base))[t];
  int tsum = v.x + v.y + v.z + v.w;
  int sc = tsum;                                   // inclusive wave scan
  for (int o = 1; o < 64; o <<= 1) {
    int u = __shfl_up(sc, o, 64);
    if (lane >= o) sc += u;
  }
  if (lane == 63) wsums[wid] = sc;
  __syncthreads();
  int woff = 0;
  for (int w = 0; w < wid; ++w) woff += wsums[w];
  int p = bsum[blockIdx.x] + woff + (sc - tsum);   // exclusive prefix of elem 0
  int e0 = base + t * 4;
  int4 r;
  r.x = p; if (v.x) { if (p < K) uniq[p] = e0 + 0; ++p; }
  r.y = p; if (v.y) { if (p < K) uniq[p] = e0 + 1; ++p; }
  r.z = p; if (v.z) { if (p < K) uniq[p] = e0 + 2; ++p; }
  r.w = p; if (v.w) { if (p < K) uniq[p] = e0 + 3; ++p; }
  ((int4*)(occ + base))[t] = r;
}

// ---- pass 2d: pflat: flat voxel id -> voxel rank (in-place) -------------
__global__ void k_remap(int* __restrict__ pflat, int n, const int* __restrict__ rank) {
  int i = blockIdx.x * blockDim.x + threadIdx.x;
  if (i >= n) return;
  int f = pflat[i];
  pflat[i] = (f >= 0) ? rank[f] : -1;
}

// ---- pass 3A: partitioned append into TRANSPOSED layout vox_t[pos][v] ---
// 8 voxel-rank partitions; partition = blockIdx & 7 so consecutive blocks
// (round-robined across XCDs) each keep their partition's 1.5 MB write
// working set resident in their own L2 -> write-combining, ~10x less
// dirty-evict HBM traffic than the voxel-major scatter.
__global__ void k_append_t(const int* __restrict__ prank, int n,
                           int* __restrict__ cnt, unsigned* __restrict__ vox_t) {
  int part = blockIdx.x & (NPART - 1);
  int i = (blockIdx.x >> 3) * blockDim.x + threadIdx.x;
  if (i >= n) return;
  int v = prank[i];
  int lo = part * PARTW;
  if (v < lo || v >= lo + PARTW) return;
  int pos = atomicAdd(&cnt[v], 1);
  if (pos < MCAP) vox_t[(size_t)pos * K + v] = (unsigned)i;
}

// ---- pass 4A: staged transpose-read + bitonic sort + gather + output ----
__global__ void __launch_bounds__(256) k_final_t(
    const float* __restrict__ pts, const unsigned* __restrict__ vox_t,
    const int* __restrict__ uniq, const int* __restrict__ cnt,
    const int* __restrict__ nuq_p, float* __restrict__ out) {
  __shared__ unsigned tile[MCAP][5];               // [pos][voxel-in-block], +1 pad
  int wid = threadIdx.x >> 6, lane = threadIdx.x & 63;
  int k0 = blockIdx.x * 4;
  int k = k0 + wid;
  // coalesced plane reads: thread p loads 4 consecutive voxels of plane p
  if (threadIdx.x < MCAP) {
    uint4 c = *(const uint4*)(vox_t + (size_t)threadIdx.x * K + k0);
    tile[threadIdx.x][0] = c.x; tile[threadIdx.x][1] = c.y;
    tile[threadIdx.x][2] = c.z; tile[threadIdx.x][3] = c.w;
  }
  __syncthreads();

  int nuq = min(nuq_p[0], K);
  int c_tot = 0, c_out = 0;
  if (k < nuq) {
    int c = cnt[k];
    c_tot = min(c, MCAP);
    c_out = min(c, P);
  }
  const unsigned UMAX = 0xffffffffu;
  unsigned v0 = (2 * lane     < c_tot) ? tile[2 * lane][wid]     : UMAX;
  unsigned v1 = (2 * lane + 1 < c_tot) ? tile[2 * lane + 1][wid] : UMAX;

  // bitonic sort of 128 keys; element e = 2*lane + r  (r = reg index)
  #pragma unroll
  for (int ph = 1; ph <= 7; ++ph) {
    int kk = 1 << ph;
    bool up = ((lane & (kk >> 1)) == 0);
    #pragma unroll
    for (int d = kk >> 1; d >= 2; d >>= 1) {
      int dl = d >> 1;
      unsigned p0 = __shfl_xor(v0, dl, 64);
      unsigned p1 = __shfl_xor(v1, dl, 64);
      bool low = ((lane & dl) == 0);
      if (low == up) { v0 = min(v0, p0); v1 = min(v1, p1); }
      else           { v0 = max(v0, p0); v1 = max(v1, p1); }
    }
    unsigned lo = min(v0, v1), hi = max(v0, v1);
    v0 = up ? lo : hi;
    v1 = up ? hi : lo;
  }

  int mys = lane >> 1, h = lane & 1;
  unsigned a0 = __shfl(v0, mys >> 1, 64);
  unsigned a1 = __shfl(v1, mys >> 1, 64);
  unsigned myidx = (mys & 1) ? a1 : a0;

  float a = 0.f, b = 0.f;
  if (mys < c_out) {
    const float* pp = pts + (size_t)myidx * 5;
    a = pp[1 + 2 * h];
    b = pp[2 + 2 * h];
  }
  float2* vout = (float2*)(out + (size_t)k * (P * 4));
  vout[lane] = make_float2(a, b);

  if (lane == 0) {
    out[OUT_CNT + k] = (float)c_out;
    int f = (k < nuq) ? uniq[k] : NVOX;
    int cb = f / (GX * GY), rem = f % (GX * GY);
    out[OUT_COR + (size_t)k * 3 + 0] = (float)cb;
    out[OUT_COR + (size_t)k * 3 + 1] = (float)(rem / GY);
    out[OUT_COR + (size_t)k * 3 + 2] = (float)(rem % GY);
  }
}

// ======== fallback path (R6): candidates voxel-major in d_out ============
__global__ void k_append(const int* __restrict__ pflat, int n,
                         const int* __restrict__ rank, int* __restrict__ cnt,
                         unsigned* __restrict__ vox) {
  int i = blockIdx.x * blockDim.x + threadIdx.x;
  if (i >= n) return;
  int f = pflat[i];
  if (f < 0) return;
  int v = rank[f];
  if (v >= K) return;
  int pos = atomicAdd(&cnt[v], 1);
  if (pos < MCAP) vox[(size_t)v * MCAP + pos] = (unsigned)i;
}

__global__ void k_append_fb(const float* __restrict__ pts, int n,
                            const int* __restrict__ rank, int* __restrict__ cnt,
                            unsigned* __restrict__ vox) {
  int i = blockIdx.x * blockDim.x + threadIdx.x;
  if (i >= n) return;
  int flat;
  if (!point_voxel(pts + (size_t)i * 5, flat)) return;
  int v = rank[flat];
  if (v >= K) return;
  int pos = atomicAdd(&cnt[v], 1);
  if (pos < MCAP) vox[(size_t)v * MCAP + pos] = (unsigned)i;
}

__global__ void __launch_bounds__(256) k_final_d(
    const float* __restrict__ pts, const int* __restrict__ uniq,
    const int* __restrict__ cnt, const int* __restrict__ nuq_p,
    float* __restrict__ out) {
  int wid = threadIdx.x >> 6, lane = threadIdx.x & 63;
  int k = blockIdx.x * 4 + wid;
  if (k >= K) return;
  int nuq = min(nuq_p[0], K);
  int c_tot = 0, c_out = 0;
  if (k < nuq) {
    int c = cnt[k];
    c_tot = min(c, MCAP);
    c_out = min(c, P);
  }
  const unsigned UMAX = 0xffffffffu;
  const unsigned* row = (const unsigned*)out + (size_t)k * MCAP;
  uint2 q = ((const uint2*)row)[lane];
  unsigned v0 = (2 * lane     < c_tot) ? q.x : UMAX;
  unsigned v1 = (2 * lane + 1 < c_tot) ? q.y : UMAX;
  #pragma unroll
  for (int ph = 1; ph <= 7; ++ph) {
    int kk = 1 << ph;
    bool up = ((lane & (kk >> 1)) == 0);
    #pragma unroll
    for (int d = kk >> 1; d >= 2; d >>= 1) {
      int dl = d >> 1;
      unsigned p0 = __shfl_xor(v0, dl, 64);
      unsigned p1 = __shfl_xor(v1, dl, 64);
      bool low = ((lane & dl) == 0);
      if (low == up) { v0 = min(v0, p0); v1 = min(v1, p1); }
      else           { v0 = max(v0, p0); v1 = max(v1, p1); }
    }
    unsigned lo = min(v0, v1), hi = max(v0, v1);
    v0 = up ? lo : hi;
    v1 = up ? hi : lo;
  }
  int mys = lane >> 1, h = lane & 1;
  unsigned a0 = __shfl(v0, mys >> 1, 64);
  unsigned a1 = __shfl(v1, mys >> 1, 64);
  unsigned myidx = (mys & 1) ? a1 : a0;
  float a = 0.f, b = 0.f;
  if (mys < c_out) {
    const float* pp = pts + (size_t)myidx * 5;
    a = pp[1 + 2 * h];
    b = pp[2 + 2 * h];
  }
  float2* vout = (float2*)(out + (size_t)k * (P * 4));
  vout[lane] = make_float2(a, b);
  if (lane == 0) {
    out[OUT_CNT + k] = (float)c_out;
    int f = (k < nuq) ? uniq[k] : NVOX;
    int cb = f / (GX * GY), rem = f % (GX * GY);
    out[OUT_COR + (size_t)k * 3 + 0] = (float)cb;
    out[OUT_COR + (size_t)k * 3 + 1] = (float)(rem / GY);
    out[OUT_COR + (size_t)k * 3 + 2] = (float)(rem % GY);
  }
}

}  // namespace

extern "C" void kernel_launch(void* const* d_in, const int* in_sizes, int n_in,
                              void* d_out, int out_size, void* d_ws, size_t ws_size,
                              hipStream_t stream) {
  const float* pts = (const float*)d_in[0];
  int n = in_sizes[0] / 5;

  int* occ  = (int*)d_ws;                  // OCC_PAD ints (becomes rank)
  int* bsum = occ + OCC_PAD;               // NBLK+1 ints
  int* uniq = bsum + (NBLK + 1);           // K ints
  int* cnt  = uniq + K;                    // K ints
  size_t base_ints = (size_t)OCC_PAD + (NBLK + 1) + K + K;
  base_ints = (base_ints + 3) & ~(size_t)3;          // 16B-align
  float* out = (float*)d_out;
  int nb_pts = (n + 255) / 256;

  size_t voxt_ints = (size_t)K * MCAP;               // 7,680,000
  size_t full_ints = base_ints + voxt_ints + (size_t)n;

  hipMemsetAsync(occ, 0, (size_t)OCC_PAD * sizeof(int), stream);
  hipMemsetAsync(cnt, 0, (size_t)K * sizeof(int), stream);

  if (ws_size >= full_ints * sizeof(int)) {
    // ---- path A: transposed candidates in ws, XCD-partitioned append ----
    unsigned* vox_t = (unsigned*)((int*)d_ws + base_ints);
    int* pflat = (int*)d_ws + base_ints + voxt_ints;
    k_mark  <<<nb_pts, 256, 0, stream>>>(pts, n, occ, pflat);
    k_bsum  <<<NBLK, 256, 0, stream>>>(occ, bsum);
    k_scanb <<<1, 1024, 0, stream>>>(bsum);
    k_rank  <<<NBLK, 256, 0, stream>>>(occ, bsum, uniq);
    k_remap <<<nb_pts, 256, 0, stream>>>(pflat, n, occ);
    k_append_t<<<nb_pts * NPART, 256, 0, stream>>>(pflat, n, cnt, vox_t);
    k_final_t<<<K / 4, 256, 0, stream>>>(pts, vox_t, uniq, cnt, bsum + NBLK, out);
  } else {
    // ---- path C (R6): candidates voxel-major in d_out -------------------
    int* pflat = (int*)d_ws + base_ints;
    bool use_pflat = ws_size >= (base_ints + (size_t)n) * sizeof(int);
    k_mark  <<<nb_pts, 256, 0, stream>>>(pts, n, occ, use_pflat ? pflat : nullptr);
    k_bsum  <<<NBLK, 256, 0, stream>>>(occ, bsum);
    k_scanb <<<1, 1024, 0, stream>>>(bsum);
    k_rank  <<<NBLK, 256, 0, stream>>>(occ, bsum, uniq);
    if (use_pflat)
      k_append<<<nb_pts, 256, 0, stream>>>(pflat, n, occ, cnt, (unsigned*)out);
    else
      k_append_fb<<<nb_pts, 256, 0, stream>>>(pts, n, occ, cnt, (unsigned*)out);
    k_final_d<<<(K + 3) / 4, 256, 0, stream>>>(pts, uniq, cnt, bsum + NBLK, out);
  }
}

// Round 8
// 197.616 us; speedup vs baseline: 1.3651x; 1.0860x over previous
//
#include <hip/hip_runtime.h>

namespace {

constexpr int GX = 400, GY = 400;
constexpr int P = 32;
constexpr int K = 60000;
constexpr int MCAP = 128;            // per-voxel candidate capacity
constexpr int NB = 4;                // batch size (fixed by dataset)
constexpr int NVOX = NB * GX * GY;   // 640000
constexpr int SCAN_CHUNK = 1024;
constexpr int NBLK = (NVOX + 1 + SCAN_CHUNK - 1) / SCAN_CHUNK;  // 626
constexpr int OCC_PAD = NBLK * SCAN_CHUNK;                      // 641024
constexpr int NPART = 8;             // XCD count; voxel-rank partitions
constexpr int PARTW = K / NPART;     // 7500

constexpr float XMINf = -20.f, YMINf = -20.f, ZMINf = -2.f;
constexpr float XMAXf =  20.f, YMAXf =  20.f, ZMAXf =  3.f;

constexpr int OUT_CNT = K * P * 4;        // 7,680,000
constexpr int OUT_COR = OUT_CNT + K;      // 7,740,000

typedef unsigned uint32x4 __attribute__((ext_vector_type(4)));
typedef float floatx2 __attribute__((ext_vector_type(2)));

// DO NOT TOUCH: this exact f32 expression matches the np reference's binning
// (R2 f32-divide and R3 f64-divide each flipped one boundary point; R4+ passed).
__device__ __forceinline__ int bin_of(float v) {
  return (int)((v + 20.0f) * 10.0f);
}

__device__ __forceinline__ bool point_voxel(const float* __restrict__ pt, int& flat) {
  float x = pt[1], y = pt[2], z = pt[3];
  bool m = (x >= XMINf) & (x < XMAXf) & (y >= YMINf) & (y < YMAXf)
         & (z >= ZMINf) & (z < ZMAXf);
  if (!m) return false;
  int bi = (int)pt[0];
  int xi = min(max(bin_of(x), 0), GX - 1);
  int yi = min(max(bin_of(y), 0), GY - 1);
  flat = bi * (GX * GY) + xi * GY + yi;
  return true;
}

// ---- pass 1: bin points -> occupancy flags (+ cached flat ids) ----------
__global__ void k_mark(const float* __restrict__ pts, int n,
                       int* __restrict__ occ, int* __restrict__ pflat) {
  int i = blockIdx.x * blockDim.x + threadIdx.x;
  if (i >= n) return;
  int flat = -1;
  if (point_voxel(pts + (size_t)i * 5, flat)) occ[flat] = 1;  // benign race
  if (pflat) pflat[i] = flat;
}

// ---- pass 2a: per-chunk sums --------------------------------------------
__global__ void k_bsum(const int* __restrict__ occ, int* __restrict__ bsum) {
  __shared__ int wsums[4];
  int t = threadIdx.x, wid = t >> 6, lane = t & 63;
  int base = blockIdx.x * SCAN_CHUNK;
  int4 v = ((const int4*)(occ + base))[t];
  int s = v.x + v.y + v.z + v.w;
  for (int o = 32; o > 0; o >>= 1) s += __shfl_xor(s, o, 64);
  if (lane == 0) wsums[wid] = s;
  __syncthreads();
  if (t == 0) bsum[blockIdx.x] = wsums[0] + wsums[1] + wsums[2] + wsums[3];
}

// ---- pass 2b: scan chunk sums (single block) ----------------------------
__global__ void k_scanb(int* __restrict__ bsum) {
  __shared__ int lds[1024];
  int t = threadIdx.x;
  int v = (t < NBLK) ? bsum[t] : 0;
  lds[t] = v;
  __syncthreads();
  for (int o = 1; o < 1024; o <<= 1) {
    int add = (t >= o) ? lds[t - o] : 0;
    __syncthreads();
    lds[t] += add;
    __syncthreads();
  }
  if (t < NBLK) bsum[t] = lds[t] - v;             // exclusive
  if (t == NBLK - 1) bsum[NBLK] = lds[t];         // total = num_unique
}

// ---- pass 2c: full exclusive scan in-place (occ -> rank), emit uniq -----
__global__ void k_rank(int* __restrict__ occ, const int* __restrict__ bsum,
                       int* __restrict__ uniq) {
  __shared__ int wsums[4];
  int t = threadIdx.x, wid = t >> 6, lane = t & 63;
  int base = blockIdx.x * SCAN_CHUNK;
  int4 v = ((const int4*)(occ + base))[t];
  int tsum = v.x + v.y + v.z + v.w;
  int sc = tsum;                                   // inclusive wave scan
  for (int o = 1; o < 64; o <<= 1) {
    int u = __shfl_up(sc, o, 64);
    if (lane >= o) sc += u;
  }
  if (lane == 63) wsums[wid] = sc;
  __syncthreads();
  int woff = 0;
  for (int w = 0; w < wid; ++w) woff += wsums[w];
  int p = bsum[blockIdx.x] + woff + (sc - tsum);   // exclusive prefix of elem 0
  int e0 = base + t * 4;
  int4 r;
  r.x = p; if (v.x) { if (p < K) uniq[p] = e0 + 0; ++p; }
  r.y = p; if (v.y) { if (p < K) uniq[p] = e0 + 1; ++p; }
  r.z = p; if (v.z) { if (p < K) uniq[p] = e0 + 2; ++p; }
  r.w = p; if (v.w) { if (p < K) uniq[p] = e0 + 3; ++p; }
  ((int4*)(occ + base))[t] = r;
}

// ---- pass 2d: pflat: flat voxel id -> voxel rank (in-place) -------------
__global__ void k_remap(int* __restrict__ pflat, int n, const int* __restrict__ rank) {
  int i = blockIdx.x * blockDim.x + threadIdx.x;
  if (i >= n) return;
  int f = pflat[i];
  pflat[i] = (f >= 0) ? rank[f] : -1;
}

// ---- pass 3A: partitioned append into TRANSPOSED layout vox_t[pos][v] ---
// partition = blockIdx & 7 (consecutive blocks round-robin across XCDs) so
// each XCD's ~1.8 MB write working set stays in its own L2. prank is read
// NON-TEMPORALLY: the 8 MB read stream must not evict the write lines
// (R7: plain reads thrashed L2 -> WRITE_SIZE 84 MB instead of ~15).
__global__ void k_append_t(const int* __restrict__ prank, int n,
                           int* __restrict__ cnt, unsigned* __restrict__ vox_t) {
  int part = blockIdx.x & (NPART - 1);
  int i = (blockIdx.x >> 3) * blockDim.x + threadIdx.x;
  if (i >= n) return;
  int v = __builtin_nontemporal_load(&prank[i]);
  int lo = part * PARTW;
  if (v < lo || v >= lo + PARTW) return;
  int pos = atomicAdd(&cnt[v], 1);
  if (pos < MCAP) vox_t[(size_t)pos * K + v] = (unsigned)i;
}

// ---- pass 4A: staged transpose-read + bitonic sort + gather + output ----
__global__ void __launch_bounds__(256) k_final_t(
    const float* __restrict__ pts, const unsigned* __restrict__ vox_t,
    const int* __restrict__ uniq, const int* __restrict__ cnt,
    const int* __restrict__ nuq_p, float* __restrict__ out) {
  __shared__ unsigned tile[MCAP][5];               // [pos][voxel-in-block], +1 pad
  __shared__ int smax;
  int wid = threadIdx.x >> 6, lane = threadIdx.x & 63;
  int k0 = blockIdx.x * 4;
  int k = k0 + wid;
  int nuq = min(nuq_p[0], K);

  if (threadIdx.x == 0) {                          // block's max candidate count
    int m0 = 0;
    #pragma unroll
    for (int j = 0; j < 4; ++j) m0 = max(m0, min(cnt[k0 + j], MCAP));
    smax = m0;
  }
  __syncthreads();
  int mc = smax;
  // coalesced plane reads, only planes that hold real candidates
  if (threadIdx.x < mc) {
    uint32x4 c = __builtin_nontemporal_load(
        (const uint32x4*)(vox_t + (size_t)threadIdx.x * K + k0));
    tile[threadIdx.x][0] = c.x; tile[threadIdx.x][1] = c.y;
    tile[threadIdx.x][2] = c.z; tile[threadIdx.x][3] = c.w;
  }
  __syncthreads();

  int c_tot = 0, c_out = 0;
  if (k < nuq) {
    int c = cnt[k];
    c_tot = min(c, MCAP);
    c_out = min(c, P);
  }
  const unsigned UMAX = 0xffffffffu;
  unsigned v0 = (2 * lane     < c_tot) ? tile[2 * lane][wid]     : UMAX;
  unsigned v1 = (2 * lane + 1 < c_tot) ? tile[2 * lane + 1][wid] : UMAX;

  // bitonic sort of 128 keys; element e = 2*lane + r  (r = reg index)
  #pragma unroll
  for (int ph = 1; ph <= 7; ++ph) {
    int kk = 1 << ph;
    bool up = ((lane & (kk >> 1)) == 0);
    #pragma unroll
    for (int d = kk >> 1; d >= 2; d >>= 1) {
      int dl = d >> 1;
      unsigned p0 = __shfl_xor(v0, dl, 64);
      unsigned p1 = __shfl_xor(v1, dl, 64);
      bool low = ((lane & dl) == 0);
      if (low == up) { v0 = min(v0, p0); v1 = min(v1, p1); }
      else           { v0 = max(v0, p0); v1 = max(v1, p1); }
    }
    unsigned lo = min(v0, v1), hi = max(v0, v1);
    v0 = up ? lo : hi;
    v1 = up ? hi : lo;
  }

  int mys = lane >> 1, h = lane & 1;
  unsigned a0 = __shfl(v0, mys >> 1, 64);
  unsigned a1 = __shfl(v1, mys >> 1, 64);
  unsigned myidx = (mys & 1) ? a1 : a0;

  float a = 0.f, b = 0.f;
  if (mys < c_out) {
    const float* pp = pts + (size_t)myidx * 5;
    a = pp[1 + 2 * h];
    b = pp[2 + 2 * h];
  }
  floatx2 val = {a, b};                            // nt store: 31 MB stream,
  __builtin_nontemporal_store(val,                 // keep L2/L3 for pts gather
      (floatx2*)(out + (size_t)k * (P * 4)) + lane);

  if (lane == 0) {
    out[OUT_CNT + k] = (float)c_out;
    int f = (k < nuq) ? uniq[k] : NVOX;
    int cb = f / (GX * GY), rem = f % (GX * GY);
    out[OUT_COR + (size_t)k * 3 + 0] = (float)cb;
    out[OUT_COR + (size_t)k * 3 + 1] = (float)(rem / GY);
    out[OUT_COR + (size_t)k * 3 + 2] = (float)(rem % GY);
  }
}

// ======== fallback path (R6): candidates voxel-major in d_out ============
__global__ void k_append(const int* __restrict__ pflat, int n,
                         const int* __restrict__ rank, int* __restrict__ cnt,
                         unsigned* __restrict__ vox) {
  int i = blockIdx.x * blockDim.x + threadIdx.x;
  if (i >= n) return;
  int f = pflat[i];
  if (f < 0) return;
  int v = rank[f];
  if (v >= K) return;
  int pos = atomicAdd(&cnt[v], 1);
  if (pos < MCAP) vox[(size_t)v * MCAP + pos] = (unsigned)i;
}

__global__ void k_append_fb(const float* __restrict__ pts, int n,
                            const int* __restrict__ rank, int* __restrict__ cnt,
                            unsigned* __restrict__ vox) {
  int i = blockIdx.x * blockDim.x + threadIdx.x;
  if (i >= n) return;
  int flat;
  if (!point_voxel(pts + (size_t)i * 5, flat)) return;
  int v = rank[flat];
  if (v >= K) return;
  int pos = atomicAdd(&cnt[v], 1);
  if (pos < MCAP) vox[(size_t)v * MCAP + pos] = (unsigned)i;
}

__global__ void __launch_bounds__(256) k_final_d(
    const float* __restrict__ pts, const int* __restrict__ uniq,
    const int* __restrict__ cnt, const int* __restrict__ nuq_p,
    float* __restrict__ out) {
  int wid = threadIdx.x >> 6, lane = threadIdx.x & 63;
  int k = blockIdx.x * 4 + wid;
  if (k >= K) return;
  int nuq = min(nuq_p[0], K);
  int c_tot = 0, c_out = 0;
  if (k < nuq) {
    int c = cnt[k];
    c_tot = min(c, MCAP);
    c_out = min(c, P);
  }
  const unsigned UMAX = 0xffffffffu;
  const unsigned* row = (const unsigned*)out + (size_t)k * MCAP;
  uint2 q = ((const uint2*)row)[lane];
  unsigned v0 = (2 * lane     < c_tot) ? q.x : UMAX;
  unsigned v1 = (2 * lane + 1 < c_tot) ? q.y : UMAX;
  #pragma unroll
  for (int ph = 1; ph <= 7; ++ph) {
    int kk = 1 << ph;
    bool up = ((lane & (kk >> 1)) == 0);
    #pragma unroll
    for (int d = kk >> 1; d >= 2; d >>= 1) {
      int dl = d >> 1;
      unsigned p0 = __shfl_xor(v0, dl, 64);
      unsigned p1 = __shfl_xor(v1, dl, 64);
      bool low = ((lane & dl) == 0);
      if (low == up) { v0 = min(v0, p0); v1 = min(v1, p1); }
      else           { v0 = max(v0, p0); v1 = max(v1, p1); }
    }
    unsigned lo = min(v0, v1), hi = max(v0, v1);
    v0 = up ? lo : hi;
    v1 = up ? hi : lo;
  }
  int mys = lane >> 1, h = lane & 1;
  unsigned a0 = __shfl(v0, mys >> 1, 64);
  unsigned a1 = __shfl(v1, mys >> 1, 64);
  unsigned myidx = (mys & 1) ? a1 : a0;
  float a = 0.f, b = 0.f;
  if (mys < c_out) {
    const float* pp = pts + (size_t)myidx * 5;
    a = pp[1 + 2 * h];
    b = pp[2 + 2 * h];
  }
  float2* vout = (float2*)(out + (size_t)k * (P * 4));
  vout[lane] = make_float2(a, b);
  if (lane == 0) {
    out[OUT_CNT + k] = (float)c_out;
    int f = (k < nuq) ? uniq[k] : NVOX;
    int cb = f / (GX * GY), rem = f % (GX * GY);
    out[OUT_COR + (size_t)k * 3 + 0] = (float)cb;
    out[OUT_COR + (size_t)k * 3 + 1] = (float)(rem / GY);
    out[OUT_COR + (size_t)k * 3 + 2] = (float)(rem % GY);
  }
}

}  // namespace

extern "C" void kernel_launch(void* const* d_in, const int* in_sizes, int n_in,
                              void* d_out, int out_size, void* d_ws, size_t ws_size,
                              hipStream_t stream) {
  const float* pts = (const float*)d_in[0];
  int n = in_sizes[0] / 5;

  int* occ  = (int*)d_ws;                  // OCC_PAD ints (becomes rank)
  int* bsum = occ + OCC_PAD;               // NBLK+1 ints
  int* uniq = bsum + (NBLK + 1);           // K ints
  int* cnt  = uniq + K;                    // K ints
  size_t base_ints = (size_t)OCC_PAD + (NBLK + 1) + K + K;
  base_ints = (base_ints + 3) & ~(size_t)3;          // 16B-align
  float* out = (float*)d_out;
  int nb_pts = (n + 255) / 256;

  size_t voxt_ints = (size_t)K * MCAP;               // 7,680,000
  size_t full_ints = base_ints + voxt_ints + (size_t)n;

  hipMemsetAsync(occ, 0, (size_t)OCC_PAD * sizeof(int), stream);
  hipMemsetAsync(cnt, 0, (size_t)K * sizeof(int), stream);

  if (ws_size >= full_ints * sizeof(int)) {
    // ---- path A: transposed candidates in ws, XCD-partitioned append ----
    unsigned* vox_t = (unsigned*)((int*)d_ws + base_ints);
    int* pflat = (int*)d_ws + base_ints + voxt_ints;
    k_mark  <<<nb_pts, 256, 0, stream>>>(pts, n, occ, pflat);
    k_bsum  <<<NBLK, 256, 0, stream>>>(occ, bsum);
    k_scanb <<<1, 1024, 0, stream>>>(bsum);
    k_rank  <<<NBLK, 256, 0, stream>>>(occ, bsum, uniq);
    k_remap <<<nb_pts, 256, 0, stream>>>(pflat, n, occ);
    k_append_t<<<nb_pts * NPART, 256, 0, stream>>>(pflat, n, cnt, vox_t);
    k_final_t<<<K / 4, 256, 0, stream>>>(pts, vox_t, uniq, cnt, bsum + NBLK, out);
  } else {
    // ---- path C (R6): candidates voxel-major in d_out -------------------
    int* pflat = (int*)d_ws + base_ints;
    bool use_pflat = ws_size >= (base_ints + (size_t)n) * sizeof(int);
    k_mark  <<<nb_pts, 256, 0, stream>>>(pts, n, occ, use_pflat ? pflat : nullptr);
    k_bsum  <<<NBLK, 256, 0, stream>>>(occ, bsum);
    k_scanb <<<1, 1024, 0, stream>>>(bsum);
    k_rank  <<<NBLK, 256, 0, stream>>>(occ, bsum, uniq);
    if (use_pflat)
      k_append<<<nb_pts, 256, 0, stream>>>(pflat, n, occ, cnt, (unsigned*)out);
    else
      k_append_fb<<<nb_pts, 256, 0, stream>>>(pts, n, occ, cnt, (unsigned*)out);
    k_final_d<<<(K + 3) / 4, 256, 0, stream>>>(pts, uniq, cnt, bsum + NBLK, out);
  }
}